// Round 1
// baseline (283.721 us; speedup 1.0000x reference)
//
#include <hip/hip_runtime.h>
#include <math.h>

#define TOKENS 16384
#define HIDDEN 2048
#define NEXP   64
#define MT     64      // tokens per block
#define KC     64      // K chunk
#define PAD_T  68      // LDS row stride (floats) for k-major staging tiles; 68*4=272 B, 16B aligned
#define PAD_E  65      // LDS row stride for logits tile

#define GATES_OFF (TOKENS * 2)
#define SEL_OFF   (GATES_OFF + TOKENS * NEXP)
#define Z_OFF     (SEL_OFF + TOKENS * 2)

__device__ __forceinline__ float wave_sum64(float v) {
    #pragma unroll
    for (int s = 1; s < 64; s <<= 1) v += __shfl_xor(v, s, 64);
    return v;
}

__global__ __launch_bounds__(256) void router_main(
    const float* __restrict__ x, const float* __restrict__ w,
    float* __restrict__ out, float* __restrict__ zpartial)
{
    __shared__ __align__(16) float smem[2 * KC * PAD_T];   // 8704 floats = 34.8 KB (reused for logits)
    __shared__ float zred[4];

    float* xs  = smem;                 // [KC][PAD_T] value xs[k][t]
    float* wsm = smem + KC * PAD_T;    // [KC][PAD_T] value wsm[k][e]

    const int tid = threadIdx.x;
    const int ti  = tid >> 4;          // 0..15 -> token group (4 tokens)
    const int tj  = tid & 15;          // 0..15 -> expert group (4 experts)
    const int t0  = blockIdx.x * MT;

    float acc[4][4];
    #pragma unroll
    for (int r = 0; r < 4; ++r)
        #pragma unroll
        for (int c = 0; c < 4; ++c) acc[r][c] = 0.f;

    const float* xbase = x + (size_t)t0 * HIDDEN;

    for (int k0 = 0; k0 < HIDDEN; k0 += KC) {
        // stage x tile: 64 tokens x 64 k = 1024 float4, 4 per thread (coalesced 256B runs)
        #pragma unroll
        for (int p = 0; p < 4; ++p) {
            const int f  = tid + 256 * p;
            const int t  = f >> 4;        // row (token)
            const int kq = f & 15;        // float4 index within row
            const float4 v = *reinterpret_cast<const float4*>(xbase + (size_t)t * HIDDEN + k0 + kq * 4);
            const int kk = kq * 4;
            xs[(kk + 0) * PAD_T + t] = v.x;
            xs[(kk + 1) * PAD_T + t] = v.y;
            xs[(kk + 2) * PAD_T + t] = v.z;
            xs[(kk + 3) * PAD_T + t] = v.w;
        }
        // stage w tile: 64 experts x 64 k
        #pragma unroll
        for (int p = 0; p < 4; ++p) {
            const int f  = tid + 256 * p;
            const int e  = f >> 4;
            const int kq = f & 15;
            const float4 v = *reinterpret_cast<const float4*>(w + (size_t)e * HIDDEN + k0 + kq * 4);
            const int kk = kq * 4;
            wsm[(kk + 0) * PAD_T + e] = v.x;
            wsm[(kk + 1) * PAD_T + e] = v.y;
            wsm[(kk + 2) * PAD_T + e] = v.z;
            wsm[(kk + 3) * PAD_T + e] = v.w;
        }
        __syncthreads();
        #pragma unroll
        for (int k = 0; k < KC; ++k) {
            const float4 a = *reinterpret_cast<const float4*>(xs  + k * PAD_T + 4 * ti);
            const float4 b = *reinterpret_cast<const float4*>(wsm + k * PAD_T + 4 * tj);
            acc[0][0] = fmaf(a.x, b.x, acc[0][0]);
            acc[0][1] = fmaf(a.x, b.y, acc[0][1]);
            acc[0][2] = fmaf(a.x, b.z, acc[0][2]);
            acc[0][3] = fmaf(a.x, b.w, acc[0][3]);
            acc[1][0] = fmaf(a.y, b.x, acc[1][0]);
            acc[1][1] = fmaf(a.y, b.y, acc[1][1]);
            acc[1][2] = fmaf(a.y, b.z, acc[1][2]);
            acc[1][3] = fmaf(a.y, b.w, acc[1][3]);
            acc[2][0] = fmaf(a.z, b.x, acc[2][0]);
            acc[2][1] = fmaf(a.z, b.y, acc[2][1]);
            acc[2][2] = fmaf(a.z, b.z, acc[2][2]);
            acc[2][3] = fmaf(a.z, b.w, acc[2][3]);
            acc[3][0] = fmaf(a.w, b.x, acc[3][0]);
            acc[3][1] = fmaf(a.w, b.y, acc[3][1]);
            acc[3][2] = fmaf(a.w, b.z, acc[3][2]);
            acc[3][3] = fmaf(a.w, b.w, acc[3][3]);
        }
        __syncthreads();
    }

    // ---- routing phase: dump logits to LDS (reuse staging memory) ----
    float* lg = smem;   // [MT][PAD_E], lg[t][e]
    #pragma unroll
    for (int r = 0; r < 4; ++r)
        #pragma unroll
        for (int c = 0; c < 4; ++c)
            lg[(4 * ti + r) * PAD_E + (4 * tj + c)] = acc[r][c];
    __syncthreads();

    const int wave = tid >> 6;   // 0..3
    const int lane = tid & 63;   // = expert index
    float zsum = 0.f;

    for (int tt = 0; tt < 16; ++tt) {
        const int t = wave * 16 + tt;
        const float v = lg[t * PAD_E + lane];

        // argmax with first-index tiebreak (matches jnp.argmax)
        float bv = v; int bi = lane;
        #pragma unroll
        for (int s = 1; s < 64; s <<= 1) {
            const float ov = __shfl_xor(bv, s, 64);
            const int   oi = __shfl_xor(bi, s, 64);
            if (ov > bv || (ov == bv && oi < bi)) { bv = ov; bi = oi; }
        }
        const float max1 = bv; const int s1 = bi;

        // original softmax + logsumexp
        const float e1 = expf(v - max1);
        const float sume = wave_sum64(e1);
        out[GATES_OFF + (size_t)(t0 + t) * NEXP + lane] = e1 / sume;
        const float lse = max1 + logf(sume);
        zsum += lse * lse;   // wave-uniform

        // top-1 pass: mask where (max1 - v) / max(|v|, max1) > 2*eps
        const bool mask1 = (max1 - v) > 0.02f * fmaxf(fabsf(v), max1);
        const float sum1 = wave_sum64(mask1 ? 0.f : e1);
        // m1 = softmax(masked)[s1] = exp(0)/sum1

        // top-2 pass: exclude s1, argmax again
        float bv2 = (lane == s1) ? -INFINITY : v; int bi2 = lane;
        #pragma unroll
        for (int s = 1; s < 64; s <<= 1) {
            const float ov = __shfl_xor(bv2, s, 64);
            const int   oi = __shfl_xor(bi2, s, 64);
            if (ov > bv2 || (ov == bv2 && oi < bi2)) { bv2 = ov; bi2 = oi; }
        }
        const float max2 = bv2; const int s2 = bi2;

        const bool mask2 = (max2 - v) > 0.02f * fmaxf(fabsf(v), max2);  // factor uses ORIGINAL logits
        const float p2 = (mask2 || lane == s1) ? 0.f : expf(v - max2);
        const float sum2 = wave_sum64(p2);

        if (lane == 0) {
            const size_t trow = (size_t)(t0 + t) * 2;
            out[trow + 0] = 1.f / sum1;
            out[trow + 1] = 1.f / sum2;
            out[SEL_OFF + trow + 0] = (float)s1;
            out[SEL_OFF + trow + 1] = (float)s2;
        }
    }

    if (lane == 0) zred[wave] = zsum;
    __syncthreads();
    if (tid == 0)
        zpartial[blockIdx.x] = zred[0] + zred[1] + zred[2] + zred[3];
}

__global__ __launch_bounds__(256) void zfinal(
    const float* __restrict__ zpartial, float* __restrict__ out)
{
    const int tid = threadIdx.x;       // 256 threads, 256 partials
    float v = zpartial[tid];
    v = wave_sum64(v);
    __shared__ float red[4];
    if ((tid & 63) == 0) red[tid >> 6] = v;
    __syncthreads();
    if (tid == 0) {
        const float tot = red[0] + red[1] + red[2] + red[3];
        out[Z_OFF] = 0.001f * (tot / (float)TOKENS);
    }
}

extern "C" void kernel_launch(void* const* d_in, const int* in_sizes, int n_in,
                              void* d_out, int out_size, void* d_ws, size_t ws_size,
                              hipStream_t stream) {
    const float* x = (const float*)d_in[0];   // [16384, 2048] fp32
    const float* w = (const float*)d_in[1];   // [64, 2048] fp32
    float* out = (float*)d_out;               // mult(32768) | gates(1048576) | sel(32768) | z(1)
    float* zpartial = (float*)d_ws;           // 256 floats

    router_main<<<TOKENS / MT, 256, 0, stream>>>(x, w, out, zpartial);
    zfinal<<<1, 256, 0, stream>>>(zpartial, out);
}